// Round 2
// 294.098 us; speedup vs baseline: 1.0125x; 1.0125x over previous
//
#include <hip/hip_runtime.h>

typedef short s16x8 __attribute__((ext_vector_type(8)));
typedef float f32x4 __attribute__((ext_vector_type(4)));
typedef float f32x2 __attribute__((ext_vector_type(2)));

// ---------------- bf16 pack/unpack (RNE) ----------------

__device__ inline unsigned pack_bf16(float a, float b) {
  unsigned ua = __float_as_uint(a), ub = __float_as_uint(b);
  ua += 0x7fffu + ((ua >> 16) & 1u);
  ub += 0x7fffu + ((ub >> 16) & 1u);
  return (ua >> 16) | (ub & 0xffff0000u);
}
__device__ inline float unpack_lo(unsigned u) { return __uint_as_float(u << 16); }
__device__ inline float unpack_hi(unsigned u) { return __uint_as_float(u & 0xffff0000u); }

// ---------------- Bucketed CSR build (R8: random-line writes -> coalesced; kept) ----------------

__global__ void kb_count(const int* __restrict__ dst, int E,
                         int* __restrict__ bucket_cnt, int NB) {
  __shared__ int h[256];
  h[threadIdx.x] = 0;
  __syncthreads();
  int i = blockIdx.x * blockDim.x + threadIdx.x;
  int stride = gridDim.x * blockDim.x;
  for (; i < E; i += stride) atomicAdd(&h[dst[i] >> 9], 1);
  __syncthreads();
  if (threadIdx.x < NB && h[threadIdx.x]) atomicAdd(&bucket_cnt[threadIdx.x], h[threadIdx.x]);
}

__global__ void kb_scan(const int* __restrict__ bucket_cnt, int NB, int E,
                        int* __restrict__ bucket_start, int* __restrict__ bucket_cursor) {
  int tid = threadIdx.x, lane = tid & 63, w = tid >> 6;
  int v = (tid < NB) ? bucket_cnt[tid] : 0;
  int x = v;
#pragma unroll
  for (int off = 1; off < 64; off <<= 1) {
    int u = __shfl_up(x, off);
    if (lane >= off) x += u;
  }
  __shared__ int ws4[4];
  if (lane == 63) ws4[w] = x;
  __syncthreads();
  int add = 0;
  for (int k = 0; k < w; ++k) add += ws4[k];
  x += add;
  int excl = x - v;
  if (tid < NB) {
    bucket_start[tid] = excl;
    bucket_cursor[tid] = excl;
  }
  if (tid == 0) bucket_start[NB] = E;
}

__global__ __launch_bounds__(256) void kb_scatter(const int* __restrict__ src,
                                                  const int* __restrict__ dst, int E,
                                                  int* __restrict__ bucket_cursor,
                                                  unsigned* __restrict__ pairs) {
  constexpr int T = 16;
  __shared__ int bin_cnt[256], bin_base[256];
  bin_cnt[threadIdx.x] = 0;
  __syncthreads();
  int base = blockIdx.x * (256 * T);
  unsigned u[T];
  int bb[T], slot[T];
#pragma unroll
  for (int t = 0; t < T; ++t) {
    int e = base + t * 256 + threadIdx.x;
    if (e < E) {
      int s = src[e], d = dst[e];
      bb[t] = d >> 9;
      u[t] = (unsigned)s | ((unsigned)(d & 511) << 17);
      slot[t] = atomicAdd(&bin_cnt[bb[t]], 1);
    } else {
      bb[t] = -1;
    }
  }
  __syncthreads();
  if (bin_cnt[threadIdx.x] > 0)
    bin_base[threadIdx.x] = atomicAdd(&bucket_cursor[threadIdx.x], bin_cnt[threadIdx.x]);
  __syncthreads();
#pragma unroll
  for (int t = 0; t < T; ++t)
    if (bb[t] >= 0) pairs[bin_base[bb[t]] + slot[t]] = u[t];
}

__global__ __launch_bounds__(256) void kc_csr(const unsigned* __restrict__ pairs,
                                              const int* __restrict__ bucket_start,
                                              int N, float* __restrict__ dinv,
                                              int* __restrict__ row_start,
                                              int* __restrict__ deg,
                                              int* __restrict__ col) {
  int b = blockIdx.x;
  int pbase = bucket_start[b], m = bucket_start[b + 1] - pbase;
  int tid = threadIdx.x, lane = tid & 63, w = tid >> 6;
  __shared__ int cnt[512], cur[512];
  __shared__ int ws4[4];
  cnt[tid] = 0;
  cnt[tid + 256] = 0;
  __syncthreads();
  for (int i = tid; i < m; i += 256) atomicAdd(&cnt[pairs[pbase + i] >> 17], 1);
  __syncthreads();
  int c0 = cnt[2 * tid], c1 = cnt[2 * tid + 1];
  int p = c0 + c1, x = p;
#pragma unroll
  for (int off = 1; off < 64; off <<= 1) {
    int uu = __shfl_up(x, off);
    if (lane >= off) x += uu;
  }
  if (lane == 63) ws4[w] = x;
  __syncthreads();
  int add = 0;
  for (int k = 0; k < w; ++k) add += ws4[k];
  x += add;
  int xe = x - p;
  cur[2 * tid] = xe;
  cur[2 * tid + 1] = xe + c0;
  int n0 = b * 512 + 2 * tid;
  if (n0 < N) {
    deg[n0] = c0;
    dinv[n0] = rsqrtf((float)(c0 + 1));
    row_start[n0] = pbase + xe;
  }
  if (n0 + 1 < N) {
    deg[n0 + 1] = c1;
    dinv[n0 + 1] = rsqrtf((float)(c1 + 1));
    row_start[n0 + 1] = pbase + xe + c0;
  }
  __syncthreads();
  for (int i = tid; i < m; i += 256) {
    unsigned uu = pairs[pbase + i];
    int pos = atomicAdd(&cur[uu >> 17], 1);
    col[pbase + pos] = (int)(uu & 131071u);
  }
}

// ---------------- W transpose + bf16 pack: WT[n][kd] = (bf16 W[2kd][n], bf16 W[2kd+1][n]) ----------------

__global__ void kw_trans(const float* __restrict__ W, int NC, int NT,
                         unsigned* __restrict__ WT) {
  int id = blockIdx.x * 256 + threadIdx.x;
  if (id >= NT * 64) return;
  int n = id >> 6, kd = id & 63;
  float a = 0.f, b = 0.f;
  if (n < NC) {
    a = W[(2 * kd) * NC + n];
    b = W[(2 * kd + 1) * NC + n];
  }
  WT[id] = pack_bf16(a, b);
}

// ---------------- MFMA GEMM: G[r,c] = bf16(dinv[r] * sum_k A[r,k]*W[k,c]) ----------------
// 16x16x32 bf16 MFMA, fp32 acc. Block 256 = 4 waves; block tile M=64.
// Verified layouts (m89/m120): A[m=lane&15][k=quad*8+j]; B[k=quad*8+j][n=lane&15];
// D[n=lane&15][m=quad*4+reg]. LDS rows padded to 68 uints.

template <int NTILES, int GSTRIDE, int NCOLS, bool A_FP32>
__global__ __launch_bounds__(256, 4) void k_gemm_mfma(const void* __restrict__ Ain,
                                                      const unsigned* __restrict__ WT,
                                                      const float* __restrict__ dinv,
                                                      unsigned* __restrict__ G, int N) {
  __shared__ unsigned Ws[NTILES * 16 * 68];
  __shared__ unsigned As[64 * 68];

  const int tid = threadIdx.x;
  const int row0 = blockIdx.x * 64;

  constexpr int WV2 = NTILES * 16 * 32;  // uint2 count
  const uint2* WT2 = (const uint2*)WT;
#pragma unroll
  for (int i = tid; i < WV2; i += 256) {
    int r = i >> 5, kd2 = i & 31;
    *(uint2*)&Ws[r * 68 + kd2 * 2] = WT2[i];
  }

  if (A_FP32) {
    const float4* X4 = (const float4*)Ain + (size_t)row0 * 32;
#pragma unroll
    for (int i = tid; i < 2048; i += 256) {
      int r = i >> 5, c4 = i & 31;
      uint2 o = {0u, 0u};
      if (row0 + r < N) {
        float4 xv = X4[i];
        o.x = pack_bf16(xv.x, xv.y);
        o.y = pack_bf16(xv.z, xv.w);
      }
      *(uint2*)&As[r * 68 + c4 * 2] = o;
    }
  } else {
    const uint2* H2 = (const uint2*)Ain + (size_t)row0 * 32;
#pragma unroll
    for (int i = tid; i < 2048; i += 256) {
      int r = i >> 5, kd2 = i & 31;
      uint2 o = {0u, 0u};
      if (row0 + r < N) o = H2[i];
      *(uint2*)&As[r * 68 + kd2 * 2] = o;
    }
  }
  __syncthreads();

  const int w = tid >> 6, lane = tid & 63;
  const int quad = lane >> 4, n16 = lane & 15;

  f32x4 acc[NTILES];
#pragma unroll
  for (int t = 0; t < NTILES; ++t) acc[t] = {0.f, 0.f, 0.f, 0.f};

  const char* Ab = (const char*)As + (w * 16 + n16) * 272 + quad * 16;
  const char* Bb = (const char*)Ws + n16 * 272 + quad * 16;
#pragma unroll
  for (int s = 0; s < 4; ++s) {
    s16x8 a = *(const s16x8*)(Ab + s * 64);
#pragma unroll
    for (int t = 0; t < NTILES; ++t) {
      s16x8 b = *(const s16x8*)(Bb + t * 16 * 272 + s * 64);
      acc[t] = __builtin_amdgcn_mfma_f32_16x16x32_bf16(a, b, acc[t], 0, 0, 0);
    }
  }

#pragma unroll
  for (int reg = 0; reg < 4; ++reg) {
    int r = row0 + w * 16 + quad * 4 + reg;
    float dv = (r < N) ? dinv[r] : 0.f;
#pragma unroll
    for (int t = 0; t < NTILES; ++t) {
      float v = acc[t][reg] * dv;
      float vp = __shfl_xor(v, 1);
      int colc = t * 16 + n16;
      if ((n16 & 1) == 0 && colc < NCOLS && r < N)
        G[(size_t)r * GSTRIDE + t * 8 + (n16 >> 1)] = pack_bf16(v, vp);
    }
  }
}

// ---------------- Aggregation 1: h2 = bf16(relu(dinv[n]*(g1[n]+sum g1[nbr]) + b1)) ----------------
// R10 redesign: was issue-bound (VALUBusy 39% = 25us of 64.5us; no pipe >50%).
// 4 neighbor rows per load instruction (dwordx4, 16 lanes x 16B = one 256B row
// per lane-quad), 32-bit offsets, col batch-loaded once per node via shfl,
// packed f32x2 accumulate. ~9-10 -> ~4.5 wave-instrs per edge.
// R11 FIX: __shfl (ds_bpermute) inside the divergent `g < pr` branch read from
// INACTIVE source lanes -> garbage neighbor index for cnt%4 != 0 (75% of nodes).
// Shuffle is now hoisted out of the branch (convergent), only the load+acc is
// predicated.

__global__ __launch_bounds__(256) void k_agg1(const unsigned* __restrict__ g1,
                                              const int* __restrict__ row_start,
                                              const int* __restrict__ deg,
                                              const int* __restrict__ col,
                                              const float* __restrict__ dinv,
                                              const float* __restrict__ b1,
                                              unsigned* __restrict__ h2, int N) {
  int node = blockIdx.x * 4 + (threadIdx.x >> 6);
  if (node >= N) return;
  const int lane = threadIdx.x & 63;
  const int g = lane >> 4;                 // edge slot within a step (0..3)
  const unsigned boff = (unsigned)(lane & 15) * 16u;  // byte offset within a 256B row
  const char* __restrict__ g1b = (const char*)g1;

  f32x2 acc0 = {0.f, 0.f}, acc1 = {0.f, 0.f}, acc2 = {0.f, 0.f}, acc3 = {0.f, 0.f};

#define ACC4(U)                                          \
  acc0 += (f32x2){unpack_lo((U).x), unpack_hi((U).x)};   \
  acc1 += (f32x2){unpack_lo((U).y), unpack_hi((U).y)};   \
  acc2 += (f32x2){unpack_lo((U).z), unpack_hi((U).z)};   \
  acc3 += (f32x2){unpack_lo((U).w), unpack_hi((U).w)};

  // self-loop contribution: quad 0 only (other quads hold 0, fixed by the reduce)
  if (g == 0) {
    uint4 su = *(const uint4*)(g1b + ((((unsigned)node) << 8) | boff));
    ACC4(su);
  }

  const int start = row_start[node], cnt = deg[node];
  if (cnt > 0) {
    const int last = start + cnt - 1;
    int j = 0;
    for (;;) {
      int ci = start + j + lane;
      int cv = col[ci < last ? ci : last];  // 64 col entries batched in registers
      int rem = cnt - j;
      if (rem >= 64) {
#pragma unroll
        for (int s = 0; s < 16; s += 4) {
          int c0 = __shfl(cv, s * 4 + g);
          int c1 = __shfl(cv, s * 4 + 4 + g);
          int c2 = __shfl(cv, s * 4 + 8 + g);
          int c3 = __shfl(cv, s * 4 + 12 + g);
          uint4 u0 = *(const uint4*)(g1b + ((((unsigned)c0) << 8) | boff));
          uint4 u1 = *(const uint4*)(g1b + ((((unsigned)c1) << 8) | boff));
          uint4 u2 = *(const uint4*)(g1b + ((((unsigned)c2) << 8) | boff));
          uint4 u3 = *(const uint4*)(g1b + ((((unsigned)c3) << 8) | boff));
          ACC4(u0);
          ACC4(u1);
          ACC4(u2);
          ACC4(u3);
        }
        j += 64;
        if (j >= cnt) break;
        continue;
      }
      // tail: rem in [1, 63]
      int fs = rem >> 2;  // full 4-edge steps
      int s = 0;
      for (; s + 4 <= fs; s += 4) {  // 16 edges, loads batched
        int c0 = __shfl(cv, s * 4 + g);
        int c1 = __shfl(cv, s * 4 + 4 + g);
        int c2 = __shfl(cv, s * 4 + 8 + g);
        int c3 = __shfl(cv, s * 4 + 12 + g);
        uint4 u0 = *(const uint4*)(g1b + ((((unsigned)c0) << 8) | boff));
        uint4 u1 = *(const uint4*)(g1b + ((((unsigned)c1) << 8) | boff));
        uint4 u2 = *(const uint4*)(g1b + ((((unsigned)c2) << 8) | boff));
        uint4 u3 = *(const uint4*)(g1b + ((((unsigned)c3) << 8) | boff));
        ACC4(u0);
        ACC4(u1);
        ACC4(u2);
        ACC4(u3);
      }
      if (s + 2 <= fs) {  // 8 edges
        int c0 = __shfl(cv, s * 4 + g);
        int c1 = __shfl(cv, s * 4 + 4 + g);
        uint4 u0 = *(const uint4*)(g1b + ((((unsigned)c0) << 8) | boff));
        uint4 u1 = *(const uint4*)(g1b + ((((unsigned)c1) << 8) | boff));
        ACC4(u0);
        ACC4(u1);
        s += 2;
      }
      if (s < fs) {  // 4 edges
        int c0 = __shfl(cv, s * 4 + g);
        uint4 u0 = *(const uint4*)(g1b + ((((unsigned)c0) << 8) | boff));
        ACC4(u0);
        ++s;
      }
      int pr = rem & 3;  // 0..3 leftover edges: quads [0, pr)
      // CONVERGENT shuffle (all 64 lanes), predicated consume only.
      int cpr = __shfl(cv, fs * 4 + g);
      if (g < pr) {
        uint4 u0 = *(const uint4*)(g1b + ((((unsigned)cpr) << 8) | boff));
        ACC4(u0);
      }
      break;
    }
  }
#undef ACC4

  // reduce partial sums across the 4 lane-quads (features are quad-invariant)
  acc0.x += __shfl_xor(acc0.x, 16);
  acc0.y += __shfl_xor(acc0.y, 16);
  acc1.x += __shfl_xor(acc1.x, 16);
  acc1.y += __shfl_xor(acc1.y, 16);
  acc2.x += __shfl_xor(acc2.x, 16);
  acc2.y += __shfl_xor(acc2.y, 16);
  acc3.x += __shfl_xor(acc3.x, 16);
  acc3.y += __shfl_xor(acc3.y, 16);
  acc0.x += __shfl_xor(acc0.x, 32);
  acc0.y += __shfl_xor(acc0.y, 32);
  acc1.x += __shfl_xor(acc1.x, 32);
  acc1.y += __shfl_xor(acc1.y, 32);
  acc2.x += __shfl_xor(acc2.x, 32);
  acc2.y += __shfl_xor(acc2.y, 32);
  acc3.x += __shfl_xor(acc3.x, 32);
  acc3.y += __shfl_xor(acc3.y, 32);

  if (g == 0) {
    float dn = dinv[node];
    int r4 = (lane & 15) * 4;
    const float2* bp = (const float2*)b1;
    float2 bb0 = bp[r4 + 0];
    float2 bb1 = bp[r4 + 1];
    float2 bb2 = bp[r4 + 2];
    float2 bb3 = bp[r4 + 3];
    uint4 o;
    o.x = pack_bf16(fmaxf(fmaf(acc0.x, dn, bb0.x), 0.f), fmaxf(fmaf(acc0.y, dn, bb0.y), 0.f));
    o.y = pack_bf16(fmaxf(fmaf(acc1.x, dn, bb1.x), 0.f), fmaxf(fmaf(acc1.y, dn, bb1.y), 0.f));
    o.z = pack_bf16(fmaxf(fmaf(acc2.x, dn, bb2.x), 0.f), fmaxf(fmaf(acc2.y, dn, bb2.y), 0.f));
    o.w = pack_bf16(fmaxf(fmaf(acc3.x, dn, bb3.x), 0.f), fmaxf(fmaf(acc3.y, dn, bb3.y), 0.f));
    *(uint4*)(h2 + (size_t)node * 64 + r4) = o;
  }
}

// ---------------- Aggregation 2: out = dinv[n]*(g2[n] + sum g2[nbr]) + b2, C=40 ----------------
// g2 packed bf16: 20 uints/row. R9 evidence: 20/64 active lanes -> issue-
// limited (1.4 TB/s, VALUBusy 25%). Now 3 nodes per wave (60/64 lanes):
// lane = sub*20 + f, 3x outstanding gathers per wave.

__global__ void k_agg2(const unsigned* __restrict__ g2, const int* __restrict__ row_start,
                       const int* __restrict__ deg, const int* __restrict__ col,
                       const float* __restrict__ dinv, const float* __restrict__ b2,
                       float* __restrict__ out, int N) {
  int lane = threadIdx.x & 63;
  int sub = lane / 20;            // 0..2 active, 3 idle
  int f = lane - sub * 20;        // 0..19
  int node = (blockIdx.x * 4 + (threadIdx.x >> 6)) * 3 + sub;
  if (sub >= 3 || node >= N) return;
  unsigned su = g2[(size_t)node * 20 + f];
  float ax = unpack_lo(su), ay = unpack_hi(su);
  int start = row_start[node], cnt = deg[node];
  int j = 0;
  for (; j + 8 <= cnt; j += 8) {
    unsigned u[8];
#pragma unroll
    for (int t = 0; t < 8; ++t)
      u[t] = g2[(size_t)col[start + j + t] * 20 + f];
#pragma unroll
    for (int t = 0; t < 8; ++t) {
      ax += unpack_lo(u[t]);
      ay += unpack_hi(u[t]);
    }
  }
  for (; j + 4 <= cnt; j += 4) {
    unsigned u[4];
#pragma unroll
    for (int t = 0; t < 4; ++t)
      u[t] = g2[(size_t)col[start + j + t] * 20 + f];
#pragma unroll
    for (int t = 0; t < 4; ++t) {
      ax += unpack_lo(u[t]);
      ay += unpack_hi(u[t]);
    }
  }
  for (; j < cnt; ++j) {
    unsigned u = g2[(size_t)col[start + j] * 20 + f];
    ax += unpack_lo(u);
    ay += unpack_hi(u);
  }
  float dn = dinv[node];
  float2 o;
  o.x = fmaf(ax, dn, b2[2 * f]);
  o.y = fmaf(ay, dn, b2[2 * f + 1]);
  *(float2*)&out[(size_t)node * 40 + 2 * f] = o;
}

// ---------------- launch ----------------

extern "C" void kernel_launch(void* const* d_in, const int* in_sizes, int n_in,
                              void* d_out, int out_size, void* d_ws, size_t ws_size,
                              hipStream_t stream) {
  const float* x = (const float*)d_in[0];
  const int* ei = (const int*)d_in[1];   // int64 in reference -> int32 on device
  const float* W1 = (const float*)d_in[2];
  const float* b1 = (const float*)d_in[3];
  const float* W2 = (const float*)d_in[4];
  const float* b2 = (const float*)d_in[5];

  const int F = in_sizes[3];       // 128
  const int N = in_sizes[0] / F;   // 100000
  const int E = in_sizes[1] / 2;   // 1600000
  const int* esrc = ei;
  const int* edst = ei + E;
  const int NB = (N + 511) / 512;  // 196

  // workspace layout (bytes):
  char* ws = (char*)d_ws;
  int* bucket_cnt = (int*)(ws + 0);
  int* bucket_start = (int*)(ws + 4096);
  int* bucket_cursor = (int*)(ws + 8192);
  unsigned* w1t = (unsigned*)(ws + 16384);
  unsigned* w2t = (unsigned*)(ws + 49152);
  float* dinv = (float*)(ws + 65536);
  int* row_start = (int*)(ws + 466944);
  int* deg = (int*)(ws + 868352);
  unsigned* pairs = (unsigned*)(ws + 1269760);
  int* colx = (int*)(ws + 7669760);
  unsigned* g1 = (unsigned*)(ws + 14073856);
  unsigned* h2 = (unsigned*)(ws + 39673856);
  unsigned* g2 = g1;  // g1 is dead after k_agg1

  hipMemsetAsync(bucket_cnt, 0, 1024, stream);

  kb_count<<<256, 256, 0, stream>>>(edst, E, bucket_cnt, NB);
  kb_scan<<<1, 256, 0, stream>>>(bucket_cnt, NB, E, bucket_start, bucket_cursor);
  kb_scatter<<<(E + 4095) / 4096, 256, 0, stream>>>(esrc, edst, E, bucket_cursor, pairs);
  kc_csr<<<NB, 256, 0, stream>>>(pairs, bucket_start, N, dinv, row_start, deg, colx);

  kw_trans<<<32, 256, 0, stream>>>(W1, 128, 128, w1t);
  kw_trans<<<12, 256, 0, stream>>>(W2, 40, 48, w2t);

  const int gblocks = (N + 63) / 64;  // 1563
  // Layer 1: NTILES=8 (NC=128), A = x fp32. LDS 52.2 KB -> 3 blocks/CU.
  k_gemm_mfma<8, 64, 128, true><<<gblocks, 256, 0, stream>>>(x, w1t, dinv, g1, N);
  k_agg1<<<(N + 3) / 4, 256, 0, stream>>>(g1, row_start, deg, colx, dinv, b1, h2, N);
  // Layer 2: NTILES=3 (NC=40, padded 48), A = h2 bf16. LDS 30.5 KB.
  k_gemm_mfma<3, 20, 40, false><<<gblocks, 256, 0, stream>>>(h2, w2t, dinv, g2, N);
  // agg2: 12 nodes per block (4 waves x 3 nodes).
  k_agg2<<<(N + 11) / 12, 256, 0, stream>>>(g2, row_start, deg, colx, dinv, b2,
                                            (float*)d_out, N);
}